// Round 10
// baseline (623.144 us; speedup 1.0000x reference)
//
#include <hip/hip_runtime.h>
#include <hip/hip_bf16.h>

#define HD 512      // d_model
#define NST 64      // d_state
#define NLAY 6
#define LSEQ 784
#define BB 64       // batch
#define NKA 848     // reversed+padded kernel array length (u16)
#define TOFF 800    // KA[t] = K[TOFF - t]; t in [17,800] real, else 0
#define LPADROWS 800  // padded L (25 tiles of 32); pad rows killed by zero-K
#define KSTR 850    // u16 stride between shifted K copies
#define CHK2 5      // 32-row l-tiles per conv block; 25 = 5*5
#define NCH 5       // chunks
#define UTS2 9      // UT row stride in dwords (8 j-pairs + 1 pad)

typedef unsigned short u16;
typedef short s8v __attribute__((ext_vector_type(8)));   // 8 bf16 (4 VGPR)
typedef float f16v __attribute__((ext_vector_type(16))); // 32x32 MFMA acc
typedef u16  u4h __attribute__((ext_vector_type(4)));    // ushort4 (8B)
typedef u16  u8h __attribute__((ext_vector_type(8)));    // ushort8 (16B)

// fp32 -> bf16 bits, round-to-nearest-even
__device__ __forceinline__ unsigned f2b(float f)
{
    unsigned u = __builtin_bit_cast(unsigned, f);
    return (u + 0x7FFFu + ((u >> 16) & 1u)) >> 16;
}
__device__ __forceinline__ float b2f16(u16 v)
{
    unsigned u = ((unsigned)v) << 16;
    return __builtin_bit_cast(float, u);
}
// pack 2 fp32 -> 2 bf16 (RNE, same rounding as f2b), lo | hi<<16
__device__ __forceinline__ unsigned pkbf(float lo, float hi)
{
    unsigned r;
    asm("v_cvt_pk_bf16_f32 %0, %1, %2" : "=v"(r) : "v"(lo), "v"(hi));
    return r;
}

// ---------------------------------------------------------------------------
// Per (layer,h,n): lambda = exp(dt*A), dtA, 2*Cd. Layout [i][h][n].
// ---------------------------------------------------------------------------
__global__ void precompute_k(const float* __restrict__ log_dt,
                             const float* __restrict__ log_A_real,
                             const float* __restrict__ A_imag,
                             const float* __restrict__ C_re,
                             const float* __restrict__ C_im,
                             float* __restrict__ lamr, float* __restrict__ lami,
                             float* __restrict__ dtr,  float* __restrict__ dti,
                             float* __restrict__ c2r,  float* __restrict__ c2i)
{
    int t = blockIdx.x * 256 + threadIdx.x;
    if (t >= NLAY * HD * NST) return;
    int ih = t >> 6;                       // i*HD + h
    float dt  = expf(log_dt[ih]);
    float are = -expf(log_A_real[t]);
    float aim = A_imag[t];
    float dr = are * dt, di = aim * dt;
    float er = expf(dr);
    float sn, cs; __sincosf(di, &sn, &cs);
    float lr = er * cs, li = er * sn;      // lambda
    float e1r = lr - 1.0f, e1i = li;
    float den = are * are + aim * aim;
    float qr = (e1r * are + e1i * aim) / den;
    float qi = (e1i * are - e1r * aim) / den;
    float crv = C_re[t], civ = C_im[t];
    lamr[t] = lr; lami[t] = li; dtr[t] = dr; dti[t] = di;
    c2r[t] = 2.0f * (crv * qr - civ * qi);
    c2i[t] = 2.0f * (crv * qi + civ * qr);
}

// ---------------------------------------------------------------------------
// Build KA[i][h][t] (bf16): reversed, zero-padded conv kernel.
// 8-way n-chain interleave: per k-step, 8 independent rotation chains
// (issue-bound, not latency-bound).  Bit-exact: each acc[k] still sums its
// terms in ascending-n order (j ascending within each group of 8).
// ---------------------------------------------------------------------------
__global__ void kq_k(const float* __restrict__ lamr, const float* __restrict__ lami,
                     const float* __restrict__ dtr,  const float* __restrict__ dti,
                     const float* __restrict__ c2r,  const float* __restrict__ c2i,
                     u16* __restrict__ KA)
{
    int t = blockIdx.x * 256 + threadIdx.x;   // < 6*512*49
    int dc = t % 49;
    int ih = t / 49;                          // i*HD + h
    int d0 = dc * 16;
    float acc[16];
#pragma unroll
    for (int k = 0; k < 16; k++) acc[k] = 0.f;
    int base = ih * 64;
    for (int n = 0; n < 64; n += 8) {
        float lr[8], li[8], cr[8], ci[8], pr[8], pi[8];
#pragma unroll
        for (int j = 0; j < 8; j++) {
            int q = base + n + j;
            lr[j] = lamr[q]; li[j] = lami[q];
            float dr = dtr[q], di = dti[q];
            cr[j] = c2r[q]; ci[j] = c2i[q];
            float e = __expf(dr * (float)d0);
            float sn, cs; __sincosf(di * (float)d0, &sn, &cs);
            pr[j] = e * cs; pi[j] = e * sn;   // lam^d0
        }
#pragma unroll
        for (int k = 0; k < 16; k++) {
#pragma unroll
            for (int j = 0; j < 8; j++) {
                acc[k] = fmaf(cr[j], pr[j], fmaf(-ci[j], pi[j], acc[k]));
                float nr = pr[j] * lr[j] - pi[j] * li[j];
                pi[j] = fmaf(pr[j], li[j], pi[j] * lr[j]);
                pr[j] = nr;
            }
        }
    }
    u16* kap = KA + (size_t)ih * NKA;
#pragma unroll
    for (int k = 0; k < 16; k++)
        kap[TOFF - (d0 + k)] = (u16)f2b(acc[k]);
    if (dc == 0)  for (int z = TOFF + 1; z < NKA; z++) kap[z] = 0;
    if (dc == 48) for (int z = 0; z < TOFF - 783; z++) kap[z] = 0;
}

// ---------------------------------------------------------------------------
// Transpose x[b][l] -> xT[l][b] (200 KB, L2-resident; cost ~2 us)
// ---------------------------------------------------------------------------
__global__ void xt_k(const float* __restrict__ x, float* __restrict__ xT)
{
    int t = blockIdx.x * 256 + threadIdx.x;   // < 784*64
    int l = t >> 6, b = t & 63;
    xT[t] = x[b * LSEQ + l];
}

// ---------------------------------------------------------------------------
// Encoder: thread = (l, h, b-oct).  Pad rows (l >= LSEQ) get ZEROS.
// ---------------------------------------------------------------------------
__global__ void encoder_k(const float* __restrict__ xT, const float* __restrict__ ew,
                          const float* __restrict__ eb, u16* __restrict__ Vb)
{
    int g = blockIdx.x * 256 + threadIdx.x;   // < 800*512*8
    int bo = g & 7;
    int h  = (g >> 3) & 511;
    int l  = g >> 12;
    uint4* dst = (uint4*)&Vb[((size_t)l * HD + h) * BB + 8 * bo];
    if (l >= LSEQ) { *dst = (uint4){0, 0, 0, 0}; return; }
    const float4* xp = (const float4*)&xT[l * BB + 8 * bo];
    float4 a0 = xp[0], a1 = xp[1];
    float w = ew[h], bb = eb[h];
    unsigned p0 = pkbf(fmaf(a0.x, w, bb), fmaf(a0.y, w, bb));
    unsigned p1 = pkbf(fmaf(a0.z, w, bb), fmaf(a0.w, w, bb));
    unsigned p2 = pkbf(fmaf(a1.x, w, bb), fmaf(a1.y, w, bb));
    unsigned p3 = pkbf(fmaf(a1.z, w, bb), fmaf(a1.w, w, bb));
    *dst = (uint4){p0, p1, p2, p3};
}

// ---------------------------------------------------------------------------
// MFMA causal-Toeplitz conv + residual via 32x32x16 bf16 MFMA.
// Round-9 structure verbatim (51 us/layer, FETCH 45 MB, LPT dispatch).
// ---------------------------------------------------------------------------
__global__ __launch_bounds__(128, 4)
void conv_k(const u16* __restrict__ Vb, u16* __restrict__ V2,
            const u16* __restrict__ KA, const float* __restrict__ Dvec)
{
    __shared__ __align__(16) u16 KR[6816];           // 8 shifted copies
    __shared__ __align__(16) unsigned UT[2][64 * UTS2];

    const int thr = threadIdx.x;
    const int h   = blockIdx.x & 511;
    const int c   = NCH - 1 - (blockIdx.x >> 9);     // 4,...,0 (LPT order)
    const int w   = thr >> 6;                // b-half (n-tile)
    const int lane = thr & 63;
    const int n2 = lane & 31;
    const int qp = lane >> 5;
    const int JTN = 10 * c + 10;

    const u16* kap = KA + (size_t)h * NKA;
    {
        int s = thr & 7, ch = thr >> 3;      // 16 chunks x 53 (covers 848)
        int i0 = ch * 53;
        int i1 = (i0 + 53 < NKA) ? (i0 + 53) : NKA;
        u16* kr = KR + KSTR * s + ((8 - s) & 7);
        for (int i = i0; i < i1; i++) kr[i] = kap[i];
    }

    const int jj = thr >> 4;
    const int bq = thr & 15;
    {   // stage tile jt=0 (j rows 0..15)
        const u16* p = &Vb[((size_t)(2 * jj) * HD + h) * BB + 4 * bq];
        u4h r0 = *(const u4h*)p;
        u4h r1 = *(const u4h*)(p + (size_t)HD * BB);
        unsigned* up = &UT[0][0];
#pragma unroll
        for (int i = 0; i < 4; i++)
            up[(4 * bq + i) * UTS2 + jj] = (unsigned)r0[i] | ((unsigned)r1[i] << 16);
    }
    __syncthreads();

    f16v acc[CHK2];
#pragma unroll
    for (int i = 0; i < CHK2; i++)
#pragma unroll
        for (int r = 0; r < 16; r++) acc[i][r] = 0.f;

    const float dcoef = 1.0f + Dvec[h];

    const int s = lane & 7;
    const u16* krb = KR + KSTR * s + ((8 - s) & 7)
                     + (TOFF - 160 * c) + 8 * qp - n2;
    const unsigned* bb0 = &UT[0][(32 * w + n2) * UTS2 + 4 * qp];
    const unsigned* bb1 = &UT[1][(32 * w + n2) * UTS2 + 4 * qp];

    for (int jt = 0; jt < JTN; ++jt) {
        u4h r0, r1;
        const bool more = (jt + 1) < JTN;
        if (more) {
            int j = 16 * (jt + 1) + 2 * jj;
            const u16* p = &Vb[((size_t)j * HD + h) * BB + 4 * bq];
            r0 = *(const u4h*)p;
            r1 = *(const u4h*)(p + (size_t)HD * BB);
        }
        const unsigned* bb = (jt & 1) ? bb1 : bb0;
        union { unsigned u[4]; s8v v; } bu;
        bu.u[0] = bb[0]; bu.u[1] = bb[1]; bu.u[2] = bb[2]; bu.u[3] = bb[3];

        const u16* ap0 = krb + 16 * jt;
#pragma unroll
        for (int lt = 0; lt < CHK2; ++lt) {
            if (jt > 10 * c + 2 * lt + 1) continue;   // tile done (uniform)
            s8v av = *(const s8v*)__builtin_assume_aligned(ap0 - 32 * lt, 16);
            acc[lt] = __builtin_amdgcn_mfma_f32_32x32x16_bf16(av, bu.v, acc[lt], 0, 0, 0);
        }
        if (more) {
            unsigned* up = &UT[(jt & 1) ^ 1][0];
#pragma unroll
            for (int i = 0; i < 4; i++)
                up[(4 * bq + i) * UTS2 + jj] = (unsigned)r0[i] | ((unsigned)r1[i] << 16);
        }
        __syncthreads();
    }

    // epilogue: V2 = bf16(y + (1+D)*u)
#pragma unroll
    for (int lt = 0; lt < CHK2; ++lt) {
        const int l0 = 32 * (5 * c + lt) + 4 * qp;
#pragma unroll
        for (int r = 0; r < 16; ++r) {
            int l = l0 + (r & 3) + 8 * (r >> 2);
            size_t a = ((size_t)l * HD + h) * BB + 32 * w + n2;
            V2[a] = (u16)f2b(fmaf(dcoef, b2f16(Vb[a]), acc[lt][r]));
        }
    }
}

// ---------------------------------------------------------------------------
// LayerNorm over h in [l][h][b]; bf16 in/out, fp32 math.
// Reduction v2: 3-round __shfl_xor butterfly over lane bits 3/4/5 (the hg
// index within a wave) collapses 8 hg-partials in-register; LDS reduce
// array shrinks 64x65 -> 8x64 and the serial final loop 64 -> 8 iters.
// Output packed with v_cvt_pk_bf16_f32 (RNE, same rounding as f2b).
// ---------------------------------------------------------------------------
__global__ __launch_bounds__(512)
void lnT_k(const u16* __restrict__ src, u16* __restrict__ dst,
           const float* __restrict__ gp, const float* __restrict__ bp)
{
    __shared__ float redS[8][64], redQ[8][64];
    __shared__ float mus[64], rss[64];
    __shared__ float gs[512], bs[512];
    const int thr = threadIdx.x;
    const int lane = thr & 63;
    const int wv = thr >> 6;          // wave 0..7
    const int bo = thr & 7;           // b = 8*bo + i
    const int hg = thr >> 3;          // h = 8*hg + k
    const size_t l = blockIdx.x;
    gs[thr] = gp[thr]; bs[thr] = bp[thr];

    const u16* sp = &src[(l * HD + hg * 8) * BB + 8 * bo];
    float v[64];                       // v[k*8+i]
    float s[8] = {0, 0, 0, 0, 0, 0, 0, 0};
    float q[8] = {0, 0, 0, 0, 0, 0, 0, 0};
#pragma unroll
    for (int k = 0; k < 8; k++) {
        u8h r = *(const u8h*)(sp + (size_t)k * BB);
#pragma unroll
        for (int i = 0; i < 8; i++) {
            float x = b2f16(r[i]);
            v[k * 8 + i] = x;
            s[i] += x;
            q[i] = fmaf(x, x, q[i]);
        }
    }
#pragma unroll
    for (int i = 0; i < 8; i++) {
        s[i] += __shfl_xor(s[i], 8);  q[i] += __shfl_xor(q[i], 8);
        s[i] += __shfl_xor(s[i], 16); q[i] += __shfl_xor(q[i], 16);
        s[i] += __shfl_xor(s[i], 32); q[i] += __shfl_xor(q[i], 32);
    }
    if (lane < 8) {                    // one lane per bo holds wave partial
#pragma unroll
        for (int i = 0; i < 8; i++) {
            redS[wv][8 * lane + i] = s[i];
            redQ[wv][8 * lane + i] = q[i];
        }
    }
    __syncthreads();
    if (thr < 64) {
        float ts = 0.f, tq = 0.f;
#pragma unroll
        for (int g = 0; g < 8; g++) { ts += redS[g][thr]; tq += redQ[g][thr]; }
        float mu = ts * (1.0f / HD);
        mus[thr] = mu;
        rss[thr] = rsqrtf(tq * (1.0f / HD) - mu * mu + 1e-5f);
    }
    __syncthreads();
    float mu[8], rs[8];
#pragma unroll
    for (int i = 0; i < 8; i++) { mu[i] = mus[8 * bo + i]; rs[i] = rss[8 * bo + i]; }
    u16* dp = &dst[(l * HD + hg * 8) * BB + 8 * bo];
#pragma unroll
    for (int k = 0; k < 8; k++) {
        float g = gs[hg * 8 + k], bb = bs[hg * 8 + k];
        float y[8];
#pragma unroll
        for (int i = 0; i < 8; i++)
            y[i] = fmaf((v[k * 8 + i] - mu[i]) * rs[i], g, bb);
        uint4 pkt = {pkbf(y[0], y[1]), pkbf(y[2], y[3]),
                     pkbf(y[4], y[5]), pkbf(y[6], y[7])};
        *(uint4*)(dp + (size_t)k * BB) = pkt;
    }
}

// ---------------------------------------------------------------------------
// Self-contained DOUBLE LayerNorm (layer-5 LN + final LN in one pass),
// same shuffle-butterfly reduction, two phases.
// ---------------------------------------------------------------------------
__global__ __launch_bounds__(512)
void lnT2s_k(const u16* __restrict__ src, u16* __restrict__ dst,
             const float* __restrict__ g5p, const float* __restrict__ b5p,
             const float* __restrict__ gp, const float* __restrict__ bp)
{
    __shared__ float redS[8][64], redQ[8][64];
    __shared__ float mu1s[64], rs1s[64], mu2s[64], rs2s[64];
    __shared__ float gs[512], bs[512];
    const int thr = threadIdx.x;
    const int lane = thr & 63;
    const int wv = thr >> 6;
    const int bo = thr & 7;           // b = 8*bo + i
    const int hg = thr >> 3;          // h = 8*hg + k
    const size_t l = blockIdx.x;
    gs[thr] = gp[thr]; bs[thr] = bp[thr];

    const u16* sp = &src[(l * HD + (size_t)hg * 8) * BB + 8 * bo];
    float v[64];                       // v[k*8+i]
    float s[8] = {0, 0, 0, 0, 0, 0, 0, 0};
    float q[8] = {0, 0, 0, 0, 0, 0, 0, 0};
#pragma unroll
    for (int k = 0; k < 8; k++) {
        u8h r = *(const u8h*)(sp + (size_t)k * BB);
#pragma unroll
        for (int i = 0; i < 8; i++) {
            float x = b2f16(r[i]);
            v[k * 8 + i] = x;
            s[i] += x;
            q[i] = fmaf(x, x, q[i]);
        }
    }
#pragma unroll
    for (int i = 0; i < 8; i++) {
        s[i] += __shfl_xor(s[i], 8);  q[i] += __shfl_xor(q[i], 8);
        s[i] += __shfl_xor(s[i], 16); q[i] += __shfl_xor(q[i], 16);
        s[i] += __shfl_xor(s[i], 32); q[i] += __shfl_xor(q[i], 32);
    }
    if (lane < 8) {
#pragma unroll
        for (int i = 0; i < 8; i++) {
            redS[wv][8 * lane + i] = s[i];
            redQ[wv][8 * lane + i] = q[i];
        }
    }
    __syncthreads();
    if (thr < 64) {
        float ts = 0.f, tq = 0.f;
#pragma unroll
        for (int g = 0; g < 8; g++) { ts += redS[g][thr]; tq += redQ[g][thr]; }
        float mu = ts * (1.0f / HD);
        mu1s[thr] = mu;
        rs1s[thr] = rsqrtf(tq * (1.0f / HD) - mu * mu + 1e-5f);
    }
    __syncthreads();
    float mu1[8], rs1[8];
#pragma unroll
    for (int i = 0; i < 8; i++) { mu1[i] = mu1s[8 * bo + i]; rs1[i] = rs1s[8 * bo + i]; }

    // second LN pass in registers: u6 = (v - mu1)*rs1*g5 + b5
    float s2[8] = {0, 0, 0, 0, 0, 0, 0, 0};
    float q2[8] = {0, 0, 0, 0, 0, 0, 0, 0};
#pragma unroll
    for (int k = 0; k < 8; k++) {
        float g5 = g5p[hg * 8 + k], b5 = b5p[hg * 8 + k];
#pragma unroll
        for (int i = 0; i < 8; i++) {
            float x = fmaf((v[k * 8 + i] - mu1[i]) * rs1[i], g5, b5);
            v[k * 8 + i] = x;
            s2[i] += x;
            q2[i] = fmaf(x, x, q2[i]);
        }
    }
#pragma unroll
    for (int i = 0; i < 8; i++) {
        s2[i] += __shfl_xor(s2[i], 8);  q2[i] += __shfl_xor(q2[i], 8);
        s2[i] += __shfl_xor(s2[i], 16); q2[i] += __shfl_xor(q2[i], 16);
        s2[i] += __shfl_xor(s2[i], 32); q2[i] += __shfl_xor(q2[i], 32);
    }
    __syncthreads();                   // redS reuse: phase-1 reads done
    if (lane < 8) {
#pragma unroll
        for (int i = 0; i < 8; i++) {
            redS[wv][8 * lane + i] = s2[i];
            redQ[wv][8 * lane + i] = q2[i];
        }
    }
    __syncthreads();
    if (thr < 64) {
        float ts = 0.f, tq = 0.f;
#pragma unroll
        for (int g = 0; g < 8; g++) { ts += redS[g][thr]; tq += redQ[g][thr]; }
        float mu = ts * (1.0f / HD);
        mu2s[thr] = mu;
        rs2s[thr] = rsqrtf(tq * (1.0f / HD) - mu * mu + 1e-5f);
    }
    __syncthreads();
    float mu2[8], rs2[8];
#pragma unroll
    for (int i = 0; i < 8; i++) { mu2[i] = mu2s[8 * bo + i]; rs2[i] = rs2s[8 * bo + i]; }
    u16* dp = &dst[(l * HD + (size_t)hg * 8) * BB + 8 * bo];
#pragma unroll
    for (int k = 0; k < 8; k++) {
        float g = gs[hg * 8 + k], bb = bs[hg * 8 + k];
        float y[8];
#pragma unroll
        for (int i = 0; i < 8; i++)
            y[i] = fmaf((v[k * 8 + i] - mu2[i]) * rs2[i], g, bb);
        uint4 pkt = {pkbf(y[0], y[1]), pkbf(y[2], y[3]),
                     pkbf(y[4], y[5]), pkbf(y[6], y[7])};
        *(uint4*)(dp + (size_t)k * BB) = pkt;
    }
}

// ---------------------------------------------------------------------------
// Coalesced two-stage mean-pool (round-9, verified ~10 us total).
// ---------------------------------------------------------------------------
__global__ __launch_bounds__(256)
void pool2_k(const u16* __restrict__ Vb, float* __restrict__ PO2)
{
    const int cb = blockIdx.x & 15;
    const int lg = blockIdx.x >> 4;          // 0..15
    const int off = cb * 2048 + threadIdx.x * 8;
    const u16* p = Vb + (size_t)(lg * 49) * (HD * BB) + off;
    float s[8] = {0, 0, 0, 0, 0, 0, 0, 0};
    for (int l = 0; l < 49; l++) {
        u8h r = *(const u8h*)p;
        p += HD * BB;
#pragma unroll
        for (int i = 0; i < 8; i++) s[i] += b2f16(r[i]);
    }
    float* q = PO2 + (size_t)lg * (HD * BB) + off;
    *(float4*)q       = (float4){s[0], s[1], s[2], s[3]};
    *(float4*)(q + 4) = (float4){s[4], s[5], s[6], s[7]};
}

// poolr_k: PO[t] = (1/LSEQ) * sum_g PO2[g][t]   (t < HD*BB)
__global__ void poolr_k(const float* __restrict__ PO2, float* __restrict__ PO)
{
    int t = blockIdx.x * 256 + threadIdx.x;
    float s = 0.f;
#pragma unroll
    for (int g = 0; g < 16; g++) s += PO2[(size_t)g * (HD * BB) + t];
    PO[t] = s * (1.0f / LSEQ);
}

// ---------------------------------------------------------------------------
// Decoder: out[b,c] = PO[:,b] . dec_w[:,c] + dec_b[c]
// ---------------------------------------------------------------------------
__global__ void dec_k(const float* __restrict__ PO, const float* __restrict__ w,
                      const float* __restrict__ bias, float* __restrict__ out)
{
    int t = blockIdx.x * 256 + threadIdx.x;
    if (t >= BB * 10) return;
    int cc = t % 10, b = t / 10;
    float acc = bias[cc];
    for (int hh = 0; hh < HD; hh++)
        acc = fmaf(PO[hh * BB + b], w[hh * 10 + cc], acc);
    out[t] = acc;
}

// ---------------------------------------------------------------------------
extern "C" void kernel_launch(void* const* d_in, const int* in_sizes, int n_in,
                              void* d_out, int out_size, void* d_ws, size_t ws_size,
                              hipStream_t stream)
{
    const float* x   = (const float*)d_in[0];
    const float* ew  = (const float*)d_in[1];
    const float* eb  = (const float*)d_in[2];
    const float* ldt = (const float*)d_in[3];
    const float* lar = (const float*)d_in[4];
    const float* aim = (const float*)d_in[5];
    const float* cre = (const float*)d_in[6];
    const float* cim = (const float*)d_in[7];
    const float* Dp  = (const float*)d_in[8];
    const float* lng = (const float*)d_in[9];
    const float* lnb = (const float*)d_in[10];
    const float* fng = (const float*)d_in[11];
    const float* fnb = (const float*)d_in[12];
    const float* dw  = (const float*)d_in[13];
    const float* db  = (const float*)d_in[14];
    float* out = (float*)d_out;

    const size_t SZB = (size_t)BB * LPADROWS * HD;   // 26,214,400 u16 slots
    const size_t PP  = (size_t)NLAY * HD * NST;      // 196,608
    u16*   Vb  = (u16*)d_ws;                // bf16 residual stream [l][h][b]
    u16*   V2  = Vb + SZB;                  // bf16 pre-LN buffer
    float* PAR = (float*)(V2 + SZB);
    float* lamr = PAR,        * lami = PAR + PP;
    float* dtr  = PAR + 2*PP, * dti  = PAR + 3*PP;
    float* c2r  = PAR + 4*PP, * c2i  = PAR + 5*PP;
    u16* KA = (u16*)(PAR + 6 * PP);                  // 6*512*848 u16
    float* PO = PAR + 6 * PP + (NLAY * HD * NKA) / 2;
    float* xT = PO + BB * HD;                        // 784*64 fp32
    float* PO2 = xT + LSEQ * BB;                     // 16 * 32768 fp32 = 2 MB

    precompute_k<<<(NLAY * HD * NST + 255) / 256, 256, 0, stream>>>(
        ldt, lar, aim, cre, cim, lamr, lami, dtr, dti, c2r, c2i);
    kq_k<<<(NLAY * HD * 49) / 256, 256, 0, stream>>>(
        lamr, lami, dtr, dti, c2r, c2i, KA);
    xt_k<<<(LSEQ * BB) / 256, 256, 0, stream>>>(x, xT);
    encoder_k<<<(LPADROWS * HD * 8) / 256, 256, 0, stream>>>(xT, ew, eb, Vb);

    // layers 0..4: conv (Vb -> V2), LN (V2 -> Vb)
    for (int i = 0; i < NLAY - 1; i++) {
        conv_k<<<512 * NCH, 128, 0, stream>>>(
            Vb, V2, KA + (size_t)i * HD * NKA, Dp + i * HD);
        lnT_k<<<LSEQ, 512, 0, stream>>>(V2, Vb, lng + i * HD, lnb + i * HD);
    }
    // layer 5: conv, then fused LN5 + final LN in one pass
    conv_k<<<512 * NCH, 128, 0, stream>>>(
        Vb, V2, KA + (size_t)5 * HD * NKA, Dp + 5 * HD);
    lnT2s_k<<<LSEQ, 512, 0, stream>>>(V2, Vb, lng + 5 * HD, lnb + 5 * HD, fng, fnb);

    pool2_k<<<256, 256, 0, stream>>>(Vb, PO2);
    poolr_k<<<(HD * BB) / 256, 256, 0, stream>>>(PO2, PO);
    dec_k<<<(BB * 10 + 255) / 256, 256, 0, stream>>>(PO, dw, db, out);
}

// Round 11
// 532.980 us; speedup vs baseline: 1.1692x; 1.1692x over previous
//
#include <hip/hip_runtime.h>
#include <hip/hip_bf16.h>

#define HD 512      // d_model
#define NST 64      // d_state
#define NLAY 6
#define LSEQ 784
#define BB 64       // batch
#define NKA 848     // reversed+padded kernel array length (u16)
#define TOFF 800    // KA[t] = K[TOFF - t]; t in [17,800] real, else 0
#define LPADROWS 800  // padded L (25 tiles of 32); pad rows killed by zero-K
#define KSTR 850    // u16 stride between shifted K copies
#define CHK2 5      // 32-row l-tiles per conv block; 25 = 5*5
#define NCH 5       // chunks
#define UTS2 9      // UT row stride in dwords (8 j-pairs + 1 pad)

typedef unsigned short u16;
typedef short s8v __attribute__((ext_vector_type(8)));   // 8 bf16 (4 VGPR)
typedef float f16v __attribute__((ext_vector_type(16))); // 32x32 MFMA acc
typedef u16  u4h __attribute__((ext_vector_type(4)));    // ushort4 (8B)
typedef u16  u8h __attribute__((ext_vector_type(8)));    // ushort8 (16B)

// fp32 -> bf16 bits, round-to-nearest-even
__device__ __forceinline__ unsigned f2b(float f)
{
    unsigned u = __builtin_bit_cast(unsigned, f);
    return (u + 0x7FFFu + ((u >> 16) & 1u)) >> 16;
}
__device__ __forceinline__ float b2f16(u16 v)
{
    unsigned u = ((unsigned)v) << 16;
    return __builtin_bit_cast(float, u);
}
// pack 2 fp32 -> 2 bf16 (RNE, same rounding as f2b), lo | hi<<16
__device__ __forceinline__ unsigned pkbf(float lo, float hi)
{
    unsigned r;
    asm("v_cvt_pk_bf16_f32 %0, %1, %2" : "=v"(r) : "v"(lo), "v"(hi));
    return r;
}

// ---------------------------------------------------------------------------
// Per (layer,h,n): lambda = exp(dt*A), dtA, 2*Cd. Layout [i][h][n].
// ---------------------------------------------------------------------------
__global__ void precompute_k(const float* __restrict__ log_dt,
                             const float* __restrict__ log_A_real,
                             const float* __restrict__ A_imag,
                             const float* __restrict__ C_re,
                             const float* __restrict__ C_im,
                             float* __restrict__ lamr, float* __restrict__ lami,
                             float* __restrict__ dtr,  float* __restrict__ dti,
                             float* __restrict__ c2r,  float* __restrict__ c2i)
{
    int t = blockIdx.x * 256 + threadIdx.x;
    if (t >= NLAY * HD * NST) return;
    int ih = t >> 6;                       // i*HD + h
    float dt  = expf(log_dt[ih]);
    float are = -expf(log_A_real[t]);
    float aim = A_imag[t];
    float dr = are * dt, di = aim * dt;
    float er = expf(dr);
    float sn, cs; __sincosf(di, &sn, &cs);
    float lr = er * cs, li = er * sn;      // lambda
    float e1r = lr - 1.0f, e1i = li;
    float den = are * are + aim * aim;
    float qr = (e1r * are + e1i * aim) / den;
    float qi = (e1i * are - e1r * aim) / den;
    float crv = C_re[t], civ = C_im[t];
    lamr[t] = lr; lami[t] = li; dtr[t] = dr; dti[t] = di;
    c2r[t] = 2.0f * (crv * qr - civ * qi);
    c2i[t] = 2.0f * (crv * qi + civ * qr);
}

// ---------------------------------------------------------------------------
// Build KA[i][h][t] (bf16): reversed, zero-padded conv kernel.
// 4-way n-chain interleave (round-9 verified: ~50 VGPR, no spill).
// Bit-exact: each acc[k] sums its terms in ascending-n order.
// NOTE: 8-way spilled (r10: WRITE 226 MB, 117 us) — do not raise ILP here.
// ---------------------------------------------------------------------------
__global__ void kq_k(const float* __restrict__ lamr, const float* __restrict__ lami,
                     const float* __restrict__ dtr,  const float* __restrict__ dti,
                     const float* __restrict__ c2r,  const float* __restrict__ c2i,
                     u16* __restrict__ KA)
{
    int t = blockIdx.x * 256 + threadIdx.x;   // < 6*512*49
    int dc = t % 49;
    int ih = t / 49;                          // i*HD + h
    int d0 = dc * 16;
    float acc[16];
#pragma unroll
    for (int k = 0; k < 16; k++) acc[k] = 0.f;
    int base = ih * 64;
    for (int n = 0; n < 64; n += 4) {
        float lr[4], li[4], cr[4], ci[4], pr[4], pi[4];
#pragma unroll
        for (int j = 0; j < 4; j++) {
            int q = base + n + j;
            lr[j] = lamr[q]; li[j] = lami[q];
            float dr = dtr[q], di = dti[q];
            cr[j] = c2r[q]; ci[j] = c2i[q];
            float e = __expf(dr * (float)d0);
            float sn, cs; __sincosf(di * (float)d0, &sn, &cs);
            pr[j] = e * cs; pi[j] = e * sn;   // lam^d0
        }
#pragma unroll
        for (int k = 0; k < 16; k++) {
#pragma unroll
            for (int j = 0; j < 4; j++) {
                acc[k] = fmaf(cr[j], pr[j], fmaf(-ci[j], pi[j], acc[k]));
                float nr = pr[j] * lr[j] - pi[j] * li[j];
                pi[j] = fmaf(pr[j], li[j], pi[j] * lr[j]);
                pr[j] = nr;
            }
        }
    }
    u16* kap = KA + (size_t)ih * NKA;
#pragma unroll
    for (int k = 0; k < 16; k++)
        kap[TOFF - (d0 + k)] = (u16)f2b(acc[k]);
    if (dc == 0)  for (int z = TOFF + 1; z < NKA; z++) kap[z] = 0;
    if (dc == 48) for (int z = 0; z < TOFF - 783; z++) kap[z] = 0;
}

// ---------------------------------------------------------------------------
// Transpose x[b][l] -> xT[l][b] (200 KB, L2-resident; cost ~2 us)
// ---------------------------------------------------------------------------
__global__ void xt_k(const float* __restrict__ x, float* __restrict__ xT)
{
    int t = blockIdx.x * 256 + threadIdx.x;   // < 784*64
    int l = t >> 6, b = t & 63;
    xT[t] = x[b * LSEQ + l];
}

// ---------------------------------------------------------------------------
// Encoder: thread = (l, h, b-oct).  Pad rows (l >= LSEQ) get ZEROS.
// ---------------------------------------------------------------------------
__global__ void encoder_k(const float* __restrict__ xT, const float* __restrict__ ew,
                          const float* __restrict__ eb, u16* __restrict__ Vb)
{
    int g = blockIdx.x * 256 + threadIdx.x;   // < 800*512*8
    int bo = g & 7;
    int h  = (g >> 3) & 511;
    int l  = g >> 12;
    uint4* dst = (uint4*)&Vb[((size_t)l * HD + h) * BB + 8 * bo];
    if (l >= LSEQ) { *dst = (uint4){0, 0, 0, 0}; return; }
    const float4* xp = (const float4*)&xT[l * BB + 8 * bo];
    float4 a0 = xp[0], a1 = xp[1];
    float w = ew[h], bb = eb[h];
    unsigned p0 = pkbf(fmaf(a0.x, w, bb), fmaf(a0.y, w, bb));
    unsigned p1 = pkbf(fmaf(a0.z, w, bb), fmaf(a0.w, w, bb));
    unsigned p2 = pkbf(fmaf(a1.x, w, bb), fmaf(a1.y, w, bb));
    unsigned p3 = pkbf(fmaf(a1.z, w, bb), fmaf(a1.w, w, bb));
    *dst = (uint4){p0, p1, p2, p3};
}

// ---------------------------------------------------------------------------
// MFMA causal-Toeplitz conv + residual via 32x32x16 bf16 MFMA.
// Round-9 structure verbatim (51 us/layer, FETCH 45 MB, LPT dispatch).
// ---------------------------------------------------------------------------
__global__ __launch_bounds__(128, 4)
void conv_k(const u16* __restrict__ Vb, u16* __restrict__ V2,
            const u16* __restrict__ KA, const float* __restrict__ Dvec)
{
    __shared__ __align__(16) u16 KR[6816];           // 8 shifted copies
    __shared__ __align__(16) unsigned UT[2][64 * UTS2];

    const int thr = threadIdx.x;
    const int h   = blockIdx.x & 511;
    const int c   = NCH - 1 - (blockIdx.x >> 9);     // 4,...,0 (LPT order)
    const int w   = thr >> 6;                // b-half (n-tile)
    const int lane = thr & 63;
    const int n2 = lane & 31;
    const int qp = lane >> 5;
    const int JTN = 10 * c + 10;

    const u16* kap = KA + (size_t)h * NKA;
    {
        int s = thr & 7, ch = thr >> 3;      // 16 chunks x 53 (covers 848)
        int i0 = ch * 53;
        int i1 = (i0 + 53 < NKA) ? (i0 + 53) : NKA;
        u16* kr = KR + KSTR * s + ((8 - s) & 7);
        for (int i = i0; i < i1; i++) kr[i] = kap[i];
    }

    const int jj = thr >> 4;
    const int bq = thr & 15;
    {   // stage tile jt=0 (j rows 0..15)
        const u16* p = &Vb[((size_t)(2 * jj) * HD + h) * BB + 4 * bq];
        u4h r0 = *(const u4h*)p;
        u4h r1 = *(const u4h*)(p + (size_t)HD * BB);
        unsigned* up = &UT[0][0];
#pragma unroll
        for (int i = 0; i < 4; i++)
            up[(4 * bq + i) * UTS2 + jj] = (unsigned)r0[i] | ((unsigned)r1[i] << 16);
    }
    __syncthreads();

    f16v acc[CHK2];
#pragma unroll
    for (int i = 0; i < CHK2; i++)
#pragma unroll
        for (int r = 0; r < 16; r++) acc[i][r] = 0.f;

    const float dcoef = 1.0f + Dvec[h];

    const int s = lane & 7;
    const u16* krb = KR + KSTR * s + ((8 - s) & 7)
                     + (TOFF - 160 * c) + 8 * qp - n2;
    const unsigned* bb0 = &UT[0][(32 * w + n2) * UTS2 + 4 * qp];
    const unsigned* bb1 = &UT[1][(32 * w + n2) * UTS2 + 4 * qp];

    for (int jt = 0; jt < JTN; ++jt) {
        u4h r0, r1;
        const bool more = (jt + 1) < JTN;
        if (more) {
            int j = 16 * (jt + 1) + 2 * jj;
            const u16* p = &Vb[((size_t)j * HD + h) * BB + 4 * bq];
            r0 = *(const u4h*)p;
            r1 = *(const u4h*)(p + (size_t)HD * BB);
        }
        const unsigned* bb = (jt & 1) ? bb1 : bb0;
        union { unsigned u[4]; s8v v; } bu;
        bu.u[0] = bb[0]; bu.u[1] = bb[1]; bu.u[2] = bb[2]; bu.u[3] = bb[3];

        const u16* ap0 = krb + 16 * jt;
#pragma unroll
        for (int lt = 0; lt < CHK2; ++lt) {
            if (jt > 10 * c + 2 * lt + 1) continue;   // tile done (uniform)
            s8v av = *(const s8v*)__builtin_assume_aligned(ap0 - 32 * lt, 16);
            acc[lt] = __builtin_amdgcn_mfma_f32_32x32x16_bf16(av, bu.v, acc[lt], 0, 0, 0);
        }
        if (more) {
            unsigned* up = &UT[(jt & 1) ^ 1][0];
#pragma unroll
            for (int i = 0; i < 4; i++)
                up[(4 * bq + i) * UTS2 + jj] = (unsigned)r0[i] | ((unsigned)r1[i] << 16);
        }
        __syncthreads();
    }

    // epilogue: V2 = bf16(y + (1+D)*u)
#pragma unroll
    for (int lt = 0; lt < CHK2; ++lt) {
        const int l0 = 32 * (5 * c + lt) + 4 * qp;
#pragma unroll
        for (int r = 0; r < 16; ++r) {
            int l = l0 + (r & 3) + 8 * (r >> 2);
            size_t a = ((size_t)l * HD + h) * BB + 32 * w + n2;
            V2[a] = (u16)f2b(fmaf(dcoef, b2f16(Vb[a]), acc[lt][r]));
        }
    }
}

// ---------------------------------------------------------------------------
// LayerNorm over h in [l][h][b]; bf16 in/out, fp32 math.
// 3-round __shfl_xor butterfly (lane bits 3/4/5 = hg-within-wave) collapses
// 8 hg-partials in-register; LDS reduce 8x64, final loop 8 iters.
// Output packed with v_cvt_pk_bf16_f32 (RNE, same rounding as f2b).
// (Round-10 verified: ~20 us total saving across 6 LN passes.)
// ---------------------------------------------------------------------------
__global__ __launch_bounds__(512)
void lnT_k(const u16* __restrict__ src, u16* __restrict__ dst,
           const float* __restrict__ gp, const float* __restrict__ bp)
{
    __shared__ float redS[8][64], redQ[8][64];
    __shared__ float mus[64], rss[64];
    __shared__ float gs[512], bs[512];
    const int thr = threadIdx.x;
    const int lane = thr & 63;
    const int wv = thr >> 6;          // wave 0..7
    const int bo = thr & 7;           // b = 8*bo + i
    const int hg = thr >> 3;          // h = 8*hg + k
    const size_t l = blockIdx.x;
    gs[thr] = gp[thr]; bs[thr] = bp[thr];

    const u16* sp = &src[(l * HD + hg * 8) * BB + 8 * bo];
    float v[64];                       // v[k*8+i]
    float s[8] = {0, 0, 0, 0, 0, 0, 0, 0};
    float q[8] = {0, 0, 0, 0, 0, 0, 0, 0};
#pragma unroll
    for (int k = 0; k < 8; k++) {
        u8h r = *(const u8h*)(sp + (size_t)k * BB);
#pragma unroll
        for (int i = 0; i < 8; i++) {
            float x = b2f16(r[i]);
            v[k * 8 + i] = x;
            s[i] += x;
            q[i] = fmaf(x, x, q[i]);
        }
    }
#pragma unroll
    for (int i = 0; i < 8; i++) {
        s[i] += __shfl_xor(s[i], 8);  q[i] += __shfl_xor(q[i], 8);
        s[i] += __shfl_xor(s[i], 16); q[i] += __shfl_xor(q[i], 16);
        s[i] += __shfl_xor(s[i], 32); q[i] += __shfl_xor(q[i], 32);
    }
    if (lane < 8) {                    // one lane per bo holds wave partial
#pragma unroll
        for (int i = 0; i < 8; i++) {
            redS[wv][8 * lane + i] = s[i];
            redQ[wv][8 * lane + i] = q[i];
        }
    }
    __syncthreads();
    if (thr < 64) {
        float ts = 0.f, tq = 0.f;
#pragma unroll
        for (int g = 0; g < 8; g++) { ts += redS[g][thr]; tq += redQ[g][thr]; }
        float mu = ts * (1.0f / HD);
        mus[thr] = mu;
        rss[thr] = rsqrtf(tq * (1.0f / HD) - mu * mu + 1e-5f);
    }
    __syncthreads();
    float mu[8], rs[8];
#pragma unroll
    for (int i = 0; i < 8; i++) { mu[i] = mus[8 * bo + i]; rs[i] = rss[8 * bo + i]; }
    u16* dp = &dst[(l * HD + hg * 8) * BB + 8 * bo];
#pragma unroll
    for (int k = 0; k < 8; k++) {
        float g = gs[hg * 8 + k], bb = bs[hg * 8 + k];
        float y[8];
#pragma unroll
        for (int i = 0; i < 8; i++)
            y[i] = fmaf((v[k * 8 + i] - mu[i]) * rs[i], g, bb);
        uint4 pkt = {pkbf(y[0], y[1]), pkbf(y[2], y[3]),
                     pkbf(y[4], y[5]), pkbf(y[6], y[7])};
        *(uint4*)(dp + (size_t)k * BB) = pkt;
    }
}

// ---------------------------------------------------------------------------
// Self-contained DOUBLE LayerNorm (layer-5 LN + final LN in one pass),
// same shuffle-butterfly reduction, two phases.
// ---------------------------------------------------------------------------
__global__ __launch_bounds__(512)
void lnT2s_k(const u16* __restrict__ src, u16* __restrict__ dst,
             const float* __restrict__ g5p, const float* __restrict__ b5p,
             const float* __restrict__ gp, const float* __restrict__ bp)
{
    __shared__ float redS[8][64], redQ[8][64];
    __shared__ float mu1s[64], rs1s[64], mu2s[64], rs2s[64];
    __shared__ float gs[512], bs[512];
    const int thr = threadIdx.x;
    const int lane = thr & 63;
    const int wv = thr >> 6;
    const int bo = thr & 7;           // b = 8*bo + i
    const int hg = thr >> 3;          // h = 8*hg + k
    const size_t l = blockIdx.x;
    gs[thr] = gp[thr]; bs[thr] = bp[thr];

    const u16* sp = &src[(l * HD + (size_t)hg * 8) * BB + 8 * bo];
    float v[64];                       // v[k*8+i]
    float s[8] = {0, 0, 0, 0, 0, 0, 0, 0};
    float q[8] = {0, 0, 0, 0, 0, 0, 0, 0};
#pragma unroll
    for (int k = 0; k < 8; k++) {
        u8h r = *(const u8h*)(sp + (size_t)k * BB);
#pragma unroll
        for (int i = 0; i < 8; i++) {
            float x = b2f16(r[i]);
            v[k * 8 + i] = x;
            s[i] += x;
            q[i] = fmaf(x, x, q[i]);
        }
    }
#pragma unroll
    for (int i = 0; i < 8; i++) {
        s[i] += __shfl_xor(s[i], 8);  q[i] += __shfl_xor(q[i], 8);
        s[i] += __shfl_xor(s[i], 16); q[i] += __shfl_xor(q[i], 16);
        s[i] += __shfl_xor(s[i], 32); q[i] += __shfl_xor(q[i], 32);
    }
    if (lane < 8) {
#pragma unroll
        for (int i = 0; i < 8; i++) {
            redS[wv][8 * lane + i] = s[i];
            redQ[wv][8 * lane + i] = q[i];
        }
    }
    __syncthreads();
    if (thr < 64) {
        float ts = 0.f, tq = 0.f;
#pragma unroll
        for (int g = 0; g < 8; g++) { ts += redS[g][thr]; tq += redQ[g][thr]; }
        float mu = ts * (1.0f / HD);
        mu1s[thr] = mu;
        rs1s[thr] = rsqrtf(tq * (1.0f / HD) - mu * mu + 1e-5f);
    }
    __syncthreads();
    float mu1[8], rs1[8];
#pragma unroll
    for (int i = 0; i < 8; i++) { mu1[i] = mu1s[8 * bo + i]; rs1[i] = rs1s[8 * bo + i]; }

    // second LN pass in registers: u6 = (v - mu1)*rs1*g5 + b5
    float s2[8] = {0, 0, 0, 0, 0, 0, 0, 0};
    float q2[8] = {0, 0, 0, 0, 0, 0, 0, 0};
#pragma unroll
    for (int k = 0; k < 8; k++) {
        float g5 = g5p[hg * 8 + k], b5 = b5p[hg * 8 + k];
#pragma unroll
        for (int i = 0; i < 8; i++) {
            float x = fmaf((v[k * 8 + i] - mu1[i]) * rs1[i], g5, b5);
            v[k * 8 + i] = x;
            s2[i] += x;
            q2[i] = fmaf(x, x, q2[i]);
        }
    }
#pragma unroll
    for (int i = 0; i < 8; i++) {
        s2[i] += __shfl_xor(s2[i], 8);  q2[i] += __shfl_xor(q2[i], 8);
        s2[i] += __shfl_xor(s2[i], 16); q2[i] += __shfl_xor(q2[i], 16);
        s2[i] += __shfl_xor(s2[i], 32); q2[i] += __shfl_xor(q2[i], 32);
    }
    __syncthreads();                   // redS reuse: phase-1 reads done
    if (lane < 8) {
#pragma unroll
        for (int i = 0; i < 8; i++) {
            redS[wv][8 * lane + i] = s2[i];
            redQ[wv][8 * lane + i] = q2[i];
        }
    }
    __syncthreads();
    if (thr < 64) {
        float ts = 0.f, tq = 0.f;
#pragma unroll
        for (int g = 0; g < 8; g++) { ts += redS[g][thr]; tq += redQ[g][thr]; }
        float mu = ts * (1.0f / HD);
        mu2s[thr] = mu;
        rs2s[thr] = rsqrtf(tq * (1.0f / HD) - mu * mu + 1e-5f);
    }
    __syncthreads();
    float mu2[8], rs2[8];
#pragma unroll
    for (int i = 0; i < 8; i++) { mu2[i] = mu2s[8 * bo + i]; rs2[i] = rs2s[8 * bo + i]; }
    u16* dp = &dst[(l * HD + (size_t)hg * 8) * BB + 8 * bo];
#pragma unroll
    for (int k = 0; k < 8; k++) {
        float g = gs[hg * 8 + k], bb = bs[hg * 8 + k];
        float y[8];
#pragma unroll
        for (int i = 0; i < 8; i++)
            y[i] = fmaf((v[k * 8 + i] - mu2[i]) * rs2[i], g, bb);
        uint4 pkt = {pkbf(y[0], y[1]), pkbf(y[2], y[3]),
                     pkbf(y[4], y[5]), pkbf(y[6], y[7])};
        *(uint4*)(dp + (size_t)k * BB) = pkt;
    }
}

// ---------------------------------------------------------------------------
// Coalesced two-stage mean-pool (round-9, verified ~10 us total).
// ---------------------------------------------------------------------------
__global__ __launch_bounds__(256)
void pool2_k(const u16* __restrict__ Vb, float* __restrict__ PO2)
{
    const int cb = blockIdx.x & 15;
    const int lg = blockIdx.x >> 4;          // 0..15
    const int off = cb * 2048 + threadIdx.x * 8;
    const u16* p = Vb + (size_t)(lg * 49) * (HD * BB) + off;
    float s[8] = {0, 0, 0, 0, 0, 0, 0, 0};
    for (int l = 0; l < 49; l++) {
        u8h r = *(const u8h*)p;
        p += HD * BB;
#pragma unroll
        for (int i = 0; i < 8; i++) s[i] += b2f16(r[i]);
    }
    float* q = PO2 + (size_t)lg * (HD * BB) + off;
    *(float4*)q       = (float4){s[0], s[1], s[2], s[3]};
    *(float4*)(q + 4) = (float4){s[4], s[5], s[6], s[7]};
}

// poolr_k: PO[t] = (1/LSEQ) * sum_g PO2[g][t]   (t < HD*BB)
__global__ void poolr_k(const float* __restrict__ PO2, float* __restrict__ PO)
{
    int t = blockIdx.x * 256 + threadIdx.x;
    float s = 0.f;
#pragma unroll
    for (int g = 0; g < 16; g++) s += PO2[(size_t)g * (HD * BB) + t];
    PO[t] = s * (1.0f / LSEQ);
}

// ---------------------------------------------------------------------------
// Decoder: out[b,c] = PO[:,b] . dec_w[:,c] + dec_b[c]
// ---------------------------------------------------------------------------
__global__ void dec_k(const float* __restrict__ PO, const float* __restrict__ w,
                      const float* __restrict__ bias, float* __restrict__ out)
{
    int t = blockIdx.x * 256 + threadIdx.x;
    if (t >= BB * 10) return;
    int cc = t % 10, b = t / 10;
    float acc = bias[cc];
    for (int hh = 0; hh < HD; hh++)
        acc = fmaf(PO[hh * BB + b], w[hh * 10 + cc], acc);
    out[t] = acc;
}

// ---------------------------------------------------------------------------
extern "C" void kernel_launch(void* const* d_in, const int* in_sizes, int n_in,
                              void* d_out, int out_size, void* d_ws, size_t ws_size,
                              hipStream_t stream)
{
    const float* x   = (const float*)d_in[0];
    const float* ew  = (const float*)d_in[1];
    const float* eb  = (const float*)d_in[2];
    const float* ldt = (const float*)d_in[3];
    const float* lar = (const float*)d_in[4];
    const float* aim = (const float*)d_in[5];
    const float* cre = (const float*)d_in[6];
    const float* cim = (const float*)d_in[7];
    const float* Dp  = (const float*)d_in[8];
    const float* lng = (const float*)d_in[9];
    const float* lnb = (const float*)d_in[10];
    const float* fng = (const float*)d_in[11];
    const float* fnb = (const float*)d_in[12];
    const float* dw  = (const float*)d_in[13];
    const float* db  = (const float*)d_in[14];
    float* out = (float*)d_out;

    const size_t SZB = (size_t)BB * LPADROWS * HD;   // 26,214,400 u16 slots
    const size_t PP  = (size_t)NLAY * HD * NST;      // 196,608
    u16*   Vb  = (u16*)d_ws;                // bf16 residual stream [l][h][b]
    u16*   V2  = Vb + SZB;                  // bf16 pre-LN buffer
    float* PAR = (float*)(V2 + SZB);
    float* lamr = PAR,        * lami = PAR + PP;
    float* dtr  = PAR + 2*PP, * dti  = PAR + 3*PP;
    float* c2r  = PAR + 4*PP, * c2i  = PAR + 5*PP;
    u16* KA = (u16*)(PAR + 6 * PP);                  // 6*512*848 u16
    float* PO = PAR + 6 * PP + (NLAY * HD * NKA) / 2;
    float* xT = PO + BB * HD;                        // 784*64 fp32
    float* PO2 = xT + LSEQ * BB;                     // 16 * 32768 fp32 = 2 MB

    precompute_k<<<(NLAY * HD * NST + 255) / 256, 256, 0, stream>>>(
        ldt, lar, aim, cre, cim, lamr, lami, dtr, dti, c2r, c2i);
    kq_k<<<(NLAY * HD * 49) / 256, 256, 0, stream>>>(
        lamr, lami, dtr, dti, c2r, c2i, KA);
    xt_k<<<(LSEQ * BB) / 256, 256, 0, stream>>>(x, xT);
    encoder_k<<<(LPADROWS * HD * 8) / 256, 256, 0, stream>>>(xT, ew, eb, Vb);

    // layers 0..4: conv (Vb -> V2), LN (V2 -> Vb)
    for (int i = 0; i < NLAY - 1; i++) {
        conv_k<<<512 * NCH, 128, 0, stream>>>(
            Vb, V2, KA + (size_t)i * HD * NKA, Dp + i * HD);
        lnT_k<<<LSEQ, 512, 0, stream>>>(V2, Vb, lng + i * HD, lnb + i * HD);
    }
    // layer 5: conv, then fused LN5 + final LN in one pass
    conv_k<<<512 * NCH, 128, 0, stream>>>(
        Vb, V2, KA + (size_t)5 * HD * NKA, Dp + 5 * HD);
    lnT2s_k<<<LSEQ, 512, 0, stream>>>(V2, Vb, lng + 5 * HD, lnb + 5 * HD, fng, fnb);

    pool2_k<<<256, 256, 0, stream>>>(Vb, PO2);
    poolr_k<<<(HD * BB) / 256, 256, 0, stream>>>(PO2, PO);
    dec_k<<<(BB * 10 + 255) / 256, 256, 0, stream>>>(PO, dw, db, out);
}